// Round 1
// baseline (837.810 us; speedup 1.0000x reference)
//
#include <hip/hip_runtime.h>
#include <cstdint>
#include <cstddef>

typedef __bf16 bf16x8 __attribute__((ext_vector_type(8)));
typedef __bf16 bf16x4 __attribute__((ext_vector_type(4)));
typedef float fx4 __attribute__((ext_vector_type(4)));

static constexpr int T = 2048;
static constexpr int C = 4096;
static constexpr int H = 32;
static constexpr int HS = 128;
static constexpr int QKV_N = 12288; // 3*C

#define MFMA16(a, b, c) __builtin_amdgcn_mfma_f32_16x16x32_bf16((a), (b), (c), 0, 0, 0)

// async global->LDS, 16B per lane. LDS dest = wave-uniform base + lane*16 (m97/m104).
__device__ __forceinline__ void async_cp16(const void* g, void* l) {
  __builtin_amdgcn_global_load_lds((const __attribute__((address_space(1))) unsigned int*)g,
                                   (__attribute__((address_space(3))) unsigned int*)l,
                                   16, 0, 0);
}

// ---------------------------------------------------------------- fp32 -> bf16
__global__ __launch_bounds__(256) void cvt_f32_to_bf16(const float* __restrict__ in,
                                                       __bf16* __restrict__ out, int n4) {
  int i = blockIdx.x * 256 + threadIdx.x;
  if (i >= n4) return;
  float4 v = ((const float4*)in)[i];
  bf16x4 o;
  o.x = (__bf16)v.x; o.y = (__bf16)v.y; o.z = (__bf16)v.z; o.w = (__bf16)v.w;
  ((bf16x4*)out)[i] = o;
}

// ---------------------------------------------------------------- GEMM C = A * B^T + bias (128^2 m97-structure)
// kept for the proj GEMM (only 128 tiles at 256^2 -> half-GPU idle there).
template <int OUT_BF16>
__global__ __launch_bounds__(256, 2) void gemm_bt(const __bf16* __restrict__ A,
                                                  const __bf16* __restrict__ B,
                                                  const float* __restrict__ bias,
                                                  void* __restrict__ Cout,
                                                  int M, int N, int K) {
  constexpr int BM = 128, BN = 128, BK = 64;
  __shared__ __align__(16) __bf16 As[BM * BK]; // 16 KiB, swizzled 16B slots
  __shared__ __align__(16) __bf16 Bs[BN * BK];
  const int tid = threadIdx.x;
  const int lane = tid & 63;
  const int wid = tid >> 6;
  const int wm = (wid >> 1) * 64;
  const int wn = (wid & 1) * 64;
  const int m0 = blockIdx.y * BM;
  const int n0 = blockIdx.x * BN;
  const int lr = lane & 15;   // frag row (A) / col (B,C)
  const int quad = lane >> 4; // k-quad for inputs, row-quad for C

  fx4 acc[4][4] = {};

  for (int k0 = 0; k0 < K; k0 += BK) {
#pragma unroll
    for (int c = 0; c < 4; ++c) {
      int chunk = wid * 4 + c;
      int s = chunk * 64 + lane;
      int r = s >> 3;
      int kc = (s & 7) ^ (r & 7);
      async_cp16(A + (size_t)(m0 + r) * K + k0 + kc * 8, &As[chunk * 512]);
      async_cp16(B + (size_t)(n0 + r) * K + k0 + kc * 8, &Bs[chunk * 512]);
    }
    __syncthreads();
#pragma unroll
    for (int ks = 0; ks < BK; ks += 32) {
      bf16x8 af[4], bfr[4];
#pragma unroll
      for (int mm = 0; mm < 4; ++mm) {
        int r = wm + mm * 16 + lr;
        int kc = (ks >> 3) + quad;
        af[mm] = *(const bf16x8*)(&As[(r * 8 + (kc ^ (r & 7))) * 8]);
      }
#pragma unroll
      for (int nn = 0; nn < 4; ++nn) {
        int r = wn + nn * 16 + lr;
        int kc = (ks >> 3) + quad;
        bfr[nn] = *(const bf16x8*)(&Bs[(r * 8 + (kc ^ (r & 7))) * 8]);
      }
#pragma unroll
      for (int mm = 0; mm < 4; ++mm)
#pragma unroll
        for (int nn = 0; nn < 4; ++nn)
          acc[mm][nn] = MFMA16(af[mm], bfr[nn], acc[mm][nn]);
    }
    __syncthreads();
  }

  // C/D layout (m89/m91 verified): col = lane&15, row = (lane>>4)*4 + reg
#pragma unroll
  for (int nn = 0; nn < 4; ++nn) {
    int col = n0 + wn + nn * 16 + lr;
    float bv = bias[col];
#pragma unroll
    for (int mm = 0; mm < 4; ++mm) {
#pragma unroll
      for (int r = 0; r < 4; ++r) {
        int row = m0 + wm + mm * 16 + quad * 4 + r;
        float v = acc[mm][nn][r] + bv;
        if (OUT_BF16)
          ((__bf16*)Cout)[(size_t)row * N + col] = (__bf16)v;
        else
          ((float*)Cout)[(size_t)row * N + col] = v;
      }
    }
  }
}

// ---------------------------------------------------------------- GEMM 256^2 8-phase (T2+T3+T4+T5+T1)
// C = A * B^T + bias. A:[M,K], B:[N,K] bf16. 512 thr (8 waves, 2Mx4N), BK=64,
// double-buffered 128 KiB LDS. Half-tiles are K-halves (256 rows x 32 cols, 16 KiB).
// Counted vmcnt(6) at phases 4/8 only; never drained to 0 in the main loop.
// LDS swizzle: 16B chunk (r,kc3) of a K-half stored at slot r*4 + (kc3 ^ (r&3)).
__device__ __forceinline__ void stage_half_256(const __bf16* __restrict__ src,
                                               __bf16* lds, int row0, int kcol0,
                                               int K, int tid) {
#pragma unroll
  for (int j2 = 0; j2 < 2; ++j2) {
    int s = j2 * 512 + tid;     // chunk id 0..1023 within the half
    int r = s >> 2;             // row 0..255
    int kc = (s & 3) ^ (r & 3); // pre-swizzled global chunk
    async_cp16(src + (size_t)(row0 + r) * K + kcol0 + kc * 8,
               lds + (size_t)(j2 * 512 + (tid & 448)) * 8); // wave-uniform base
  }
}

#define GBAR()                                  \
  do {                                          \
    __builtin_amdgcn_sched_barrier(0);          \
    asm volatile("s_barrier" ::: "memory");     \
    __builtin_amdgcn_sched_barrier(0);          \
  } while (0)

// one phase: {ds-read frag subtile; stage-issue; barrier; lgkmcnt(0); setprio+16 MFMA; tail-wait; barrier}
#define PHASE(P, KK, MMB, LOADB, STAGE_STMT, TAILWAIT)                          \
  {                                                                             \
    const __bf16* Ah = &As[P][KK][0];                                           \
    const __bf16* Bh = &Bs[P][KK][0];                                           \
    bf16x8 af[4];                                                               \
    _Pragma("unroll") for (int m_ = 0; m_ < 4; ++m_) {                          \
      int r_ = (wr << 7) + (MMB + m_) * 16 + lr;                                \
      af[m_] = *(const bf16x8*)(Ah + ((r_ << 2) + (quad ^ (r_ & 3))) * 8);      \
    }                                                                           \
    if (LOADB) {                                                                \
      _Pragma("unroll") for (int n_ = 0; n_ < 4; ++n_) {                        \
        int r_ = (wc << 6) + n_ * 16 + lr;                                      \
        bfr[n_] = *(const bf16x8*)(Bh + ((r_ << 2) + (quad ^ (r_ & 3))) * 8);   \
      }                                                                         \
    }                                                                           \
    STAGE_STMT;                                                                 \
    GBAR();                                                                     \
    asm volatile("s_waitcnt lgkmcnt(0)" ::: "memory");                          \
    __builtin_amdgcn_sched_barrier(0);                                          \
    __builtin_amdgcn_s_setprio(1);                                              \
    _Pragma("unroll") for (int m_ = 0; m_ < 4; ++m_)                            \
      _Pragma("unroll") for (int n_ = 0; n_ < 4; ++n_)                          \
        acc[MMB + m_][n_] = MFMA16(af[m_], bfr[n_], acc[MMB + m_][n_]);         \
    __builtin_amdgcn_s_setprio(0);                                              \
    TAILWAIT;                                                                   \
    GBAR();                                                                     \
  }

template <int OUT_BF16>
__global__ __launch_bounds__(512, 2) void gemm_bt_256(const __bf16* __restrict__ A,
                                                      const __bf16* __restrict__ B,
                                                      const float* __restrict__ bias,
                                                      void* __restrict__ Cout,
                                                      int M, int N, int K) {
  __shared__ __align__(16) __bf16 As[2][2][8192]; // [buf][khalf][256r x 4chunks x 8] = 64 KiB
  __shared__ __align__(16) __bf16 Bs[2][2][8192]; // 64 KiB
  const int tid = threadIdx.x;
  const int lane = tid & 63;
  const int wid = tid >> 6;
  const int wr = wid >> 2; // 0..1 -> 128-row block
  const int wc = wid & 3;  // 0..3 -> 64-col block
  const int lr = lane & 15;
  const int quad = lane >> 4;

  // T1: bijective XCD-chunked swizzle (nwg % 8 == 0 for our launches)
  int nwg = gridDim.x * gridDim.y;
  int orig = blockIdx.y * gridDim.x + blockIdx.x;
  int swz = orig;
  if ((nwg & 7) == 0) swz = (orig & 7) * (nwg >> 3) + (orig >> 3);
  const int m0 = (swz / gridDim.x) * 256;
  const int n0 = (swz % gridDim.x) * 256;

  fx4 acc[8][4] = {};
  bf16x8 bfr[4];

  const int NT = K >> 6; // 64-wide K tiles (K % 128 == 0)
  const int NPAIR = NT >> 1;

  // prologue: t0 all 4 halves, vmcnt(4); t1 first 3 halves, vmcnt(6)  (m201 recipe)
  stage_half_256(B, &Bs[0][0][0], n0, 0, K, tid);
  stage_half_256(A, &As[0][0][0], m0, 0, K, tid);
  stage_half_256(B, &Bs[0][1][0], n0, 32, K, tid);
  stage_half_256(A, &As[0][1][0], m0, 32, K, tid);
  asm volatile("s_waitcnt vmcnt(4)" ::: "memory");
  stage_half_256(B, &Bs[1][0][0], n0, 64, K, tid);
  stage_half_256(A, &As[1][0][0], m0, 64, K, tid);
  stage_half_256(B, &Bs[1][1][0], n0, 96, K, tid);
  asm volatile("s_waitcnt vmcnt(6)" ::: "memory");
  GBAR();

  // steady state: iteration computes tiles a=2i (buf0, ph1-4) and a+1 (buf1, ph5-8).
  // stage schedule (each target region freed by the previous phase's closing barrier):
  //  ph1:(a+1).A.k1  ph2:(a+2).B.k0  ph3:(a+2).A.k0  ph4:(a+2).B.k1 +vmcnt(6)
  //  ph5:(a+2).A.k1  ph6:(a+3).B.k0  ph7:(a+3).A.k0  ph8:(a+3).B.k1 +vmcnt(6)
  for (int i = 0; i + 1 < NPAIR; ++i) {
    const int k1 = (2 * i + 1) << 6;
    const int k2 = (2 * i + 2) << 6;
    const int k3 = (2 * i + 3) << 6;
    PHASE(0, 0, 0, 1, stage_half_256(A, &As[1][1][0], m0, k1 + 32, K, tid), );
    PHASE(0, 0, 4, 0, stage_half_256(B, &Bs[0][0][0], n0, k2, K, tid), );
    PHASE(0, 1, 0, 1, stage_half_256(A, &As[0][0][0], m0, k2, K, tid), );
    PHASE(0, 1, 4, 0, stage_half_256(B, &Bs[0][1][0], n0, k2 + 32, K, tid),
          asm volatile("s_waitcnt vmcnt(6)" ::: "memory"));
    PHASE(1, 0, 0, 1, stage_half_256(A, &As[0][1][0], m0, k2 + 32, K, tid), );
    PHASE(1, 0, 4, 0, stage_half_256(B, &Bs[1][0][0], n0, k3, K, tid), );
    PHASE(1, 1, 0, 1, stage_half_256(A, &As[1][0][0], m0, k3, K, tid), );
    PHASE(1, 1, 4, 0, stage_half_256(B, &Bs[1][1][0], n0, k3 + 32, K, tid),
          asm volatile("s_waitcnt vmcnt(6)" ::: "memory"));
  }
  // epilogue iteration: tiles NT-2 (buf0), NT-1 (buf1); drain 4 -> 2 -> 0
  {
    const int k1 = (NT - 1) << 6;
    PHASE(0, 0, 0, 1, stage_half_256(A, &As[1][1][0], m0, k1 + 32, K, tid), );
    PHASE(0, 0, 4, 0, , asm volatile("s_waitcnt vmcnt(4)" ::: "memory"));
    PHASE(0, 1, 0, 1, , asm volatile("s_waitcnt vmcnt(2)" ::: "memory"));
    PHASE(0, 1, 4, 0, , asm volatile("s_waitcnt vmcnt(0)" ::: "memory"));
    PHASE(1, 0, 0, 1, , );
    PHASE(1, 0, 4, 0, , );
    PHASE(1, 1, 0, 1, , );
    PHASE(1, 1, 4, 0, , );
  }

  // C/D layout (m89/m91): col = lane&15, row = (lane>>4)*4 + reg
#pragma unroll
  for (int nn = 0; nn < 4; ++nn) {
    int col = n0 + (wc << 6) + nn * 16 + lr;
    float bv = bias[col];
#pragma unroll
    for (int mm = 0; mm < 8; ++mm) {
#pragma unroll
      for (int r = 0; r < 4; ++r) {
        int row = m0 + (wr << 7) + mm * 16 + quad * 4 + r;
        float v = acc[mm][nn][r] + bv;
        if (OUT_BF16)
          ((__bf16*)Cout)[(size_t)row * N + col] = (__bf16)v;
        else
          ((float*)Cout)[(size_t)row * N + col] = v;
      }
    }
  }
}

// ---------------------------------------------------------------- RoPE in-place on qkv (q and k, dims 0..31)
__global__ __launch_bounds__(256) void rope_kernel(__bf16* __restrict__ qkv,
                                                   const float* __restrict__ cosp,
                                                   const float* __restrict__ sinp) {
  int tid = blockIdx.x * 256 + threadIdx.x; // total 2048*32*2*16
  int d = tid & 15;
  int which = (tid >> 4) & 1;
  int h = (tid >> 5) & 31;
  int t = tid >> 10;
  size_t base = (size_t)t * QKV_N + h * 384 + which * 128;
  float x1 = (float)qkv[base + d];
  float x2 = (float)qkv[base + d + 16];
  float c1 = cosp[t * 32 + d], s1 = sinp[t * 32 + d];
  float c2 = cosp[t * 32 + d + 16], s2 = sinp[t * 32 + d + 16];
  qkv[base + d] = (__bf16)(x1 * c1 - x2 * s1);
  qkv[base + d + 16] = (__bf16)(x2 * c2 + x1 * s2);
}

// ---------------------------------------------------------------- V transpose: vt[h][d][t] = v[h][t][d]
__global__ __launch_bounds__(256) void vtrans_kernel(const __bf16* __restrict__ qkv,
                                                     __bf16* __restrict__ vt) {
  __shared__ __align__(16) __bf16 tile[64][136];
  int h = blockIdx.x;
  int t0 = blockIdx.y * 64;
  int tid = threadIdx.x;
#pragma unroll
  for (int c = 0; c < 4; ++c) {
    int i = tid + c * 256;
    int tl = i >> 4;
    int dp = (i & 15) * 8;
    *(uint4*)(&tile[tl][dp]) = *(const uint4*)(qkv + (size_t)(t0 + tl) * QKV_N + h * 384 + 256 + dp);
  }
  __syncthreads();
#pragma unroll
  for (int c = 0; c < 4; ++c) {
    int o = tid + c * 256;   // 0..1023
    int d = o >> 3;          // 0..127
    int ts = (o & 7) * 8;    // t segment
    bf16x8 v;
#pragma unroll
    for (int j = 0; j < 8; ++j) v[j] = tile[ts + j][d];
    *(bf16x8*)(vt + ((size_t)h * 128 + d) * T + t0 + ts) = v;
  }
}

// ---------------------------------------------------------------- flash-style causal attention, NO-MAX softmax
__global__ __launch_bounds__(256, 2) void attn_kernel(const __bf16* __restrict__ qkv,
                                                      const __bf16* __restrict__ vt,
                                                      __bf16* __restrict__ y) {
  constexpr int KT = 64;
  constexpr int LPS = KT + 8; // 72
  __shared__ __align__(16) __bf16 Ks[KT * HS];  // 16 KiB swizzled
  __shared__ __align__(16) __bf16 Vs[HS * KT];  // 16 KiB swizzled
  __shared__ __align__(16) __bf16 Ps[4][16 * LPS];

  const int h = blockIdx.x;
  const int qb = blockIdx.y;
  const int q0 = qb * 64;
  const int tid = threadIdx.x;
  const int lane = tid & 63;
  const int wid = tid >> 6;
  const int lr = lane & 15;
  const int quad = lane >> 4;
  const int qrow = q0 + wid * 16;

  bf16x8 qf[4];
#pragma unroll
  for (int kk = 0; kk < 4; ++kk)
    qf[kk] = *(const bf16x8*)(qkv + (size_t)(qrow + lr) * QKV_N + h * 384 + kk * 32 + quad * 8);

  float lsum[4];
  fx4 acc_o[8];
#pragma unroll
  for (int r = 0; r < 4; ++r) lsum[r] = 0.f;
#pragma unroll
  for (int dd = 0; dd < 8; ++dd) acc_o[dd] = (fx4)0.f;

  const float c_e2 = 0.08838834764831845f * 1.4426950408889634f;
  const int ntiles = qb + 1;
  for (int kt = 0; kt < ntiles; ++kt) {
    const int kbase = kt * KT;
#pragma unroll
    for (int c = 0; c < 4; ++c) {
      int chunk = wid * 4 + c;
      int s = chunk * 64 + lane;
      int r = s >> 4;
      int kc = (s & 15) ^ (r & 15);
      async_cp16(qkv + (size_t)(kbase + r) * QKV_N + h * 384 + 128 + kc * 8, &Ks[chunk * 512]);
    }
#pragma unroll
    for (int c = 0; c < 4; ++c) {
      int chunk = wid * 4 + c;
      int s = chunk * 64 + lane;
      int r = s >> 3;
      int kc = (s & 7) ^ (r & 7);
      async_cp16(vt + ((size_t)h * 128 + r) * T + kbase + kc * 8, &Vs[chunk * 512]);
    }
    __syncthreads();

    fx4 sv[4] = {};
#pragma unroll
    for (int nn = 0; nn < 4; ++nn) {
#pragma unroll
      for (int kk = 0; kk < 4; ++kk) {
        int r = nn * 16 + lr;
        int kc = kk * 4 + quad;
        bf16x8 kf = *(const bf16x8*)(&Ks[(r * 16 + (kc ^ (r & 15))) * 8]);
        sv[nn] = MFMA16(qf[kk], kf, sv[nn]);
      }
    }

#pragma unroll
    for (int nn = 0; nn < 4; ++nn) {
      int kj = kbase + nn * 16 + lr;
#pragma unroll
      for (int r = 0; r < 4; ++r) {
        int qi = qrow + quad * 4 + r;
        float p = __builtin_amdgcn_exp2f(sv[nn][r] * c_e2);
        p = (kj > qi) ? 0.f : p;
        lsum[r] += p;
        Ps[wid][(quad * 4 + r) * LPS + nn * 16 + lr] = (__bf16)p;
      }
    }
    asm volatile("s_waitcnt lgkmcnt(0)" ::: "memory");

#pragma unroll
    for (int kc0 = 0; kc0 < 2; ++kc0) {
      bf16x8 pf = *(const bf16x8*)(&Ps[wid][lr * LPS + kc0 * 32 + quad * 8]);
#pragma unroll
      for (int dd = 0; dd < 8; ++dd) {
        int r = dd * 16 + lr;
        int kc = kc0 * 4 + quad;
        bf16x8 vf = *(const bf16x8*)(&Vs[(r * 8 + (kc ^ (r & 7))) * 8]);
        acc_o[dd] = MFMA16(pf, vf, acc_o[dd]);
      }
    }
    __syncthreads();
  }

#pragma unroll
  for (int off = 1; off < 16; off <<= 1)
#pragma unroll
    for (int r = 0; r < 4; ++r)
      lsum[r] += __shfl_xor(lsum[r], off, 64);
#pragma unroll
  for (int r = 0; r < 4; ++r) lsum[r] = 1.0f / lsum[r];

#pragma unroll
  for (int dd = 0; dd < 8; ++dd)
#pragma unroll
    for (int r = 0; r < 4; ++r) {
      int row = qrow + quad * 4 + r;
      int col = h * 128 + dd * 16 + lr;
      y[(size_t)row * C + col] = (__bf16)(acc_o[dd][r] * lsum[r]);
    }
}

// ---------------------------------------------------------------- launcher
extern "C" void kernel_launch(void* const* d_in, const int* in_sizes, int n_in,
                              void* d_out, int out_size, void* d_ws, size_t ws_size,
                              hipStream_t stream) {
  const float* x      = (const float*)d_in[0];
  const float* cosp   = (const float*)d_in[1];
  const float* sinp   = (const float*)d_in[2];
  const float* W_attn = (const float*)d_in[3];
  const float* b_attn = (const float*)d_in[4];
  const float* W_proj = (const float*)d_in[5];
  const float* b_proj = (const float*)d_in[6];
  float* out = (float*)d_out;

  char* wsb = (char*)d_ws;
  __bf16* Wab  = (__bf16*)(wsb + 0);          // 12288*4096*2 = 100663296
  __bf16* Wpb  = (__bf16*)(wsb + 100663296);  // 4096*4096*2  =  33554432
  __bf16* xb   = (__bf16*)(wsb + 134217728);  // 2048*4096*2  =  16777216
  __bf16* qkvb = (__bf16*)(wsb + 150994944);  // 2048*12288*2 =  50331648
  __bf16* yb   = (__bf16*)(wsb + 201326592);  // 2048*4096*2  =  16777216
  __bf16* vtb  = (__bf16*)(wsb + 218103808);  // 32*128*2048*2=  16777216

  cvt_f32_to_bf16<<<8192, 256, 0, stream>>>(x, xb, (T * C) / 4);
  cvt_f32_to_bf16<<<49152, 256, 0, stream>>>(W_attn, Wab, (QKV_N * C) / 4);
  cvt_f32_to_bf16<<<16384, 256, 0, stream>>>(W_proj, Wpb, (C * C) / 4);

  // qkv = x @ W_attn^T + b_attn   (M=2048, N=12288, K=4096) — 256^2 8-phase
  gemm_bt_256<1><<<dim3(48, 8), 512, 0, stream>>>(xb, Wab, b_attn, (void*)qkvb, T, QKV_N, C);

  rope_kernel<<<8192, 256, 0, stream>>>(qkvb, cosp, sinp);
  vtrans_kernel<<<dim3(32, 32), 256, 0, stream>>>(qkvb, vtb);

  attn_kernel<<<dim3(32, 32), 256, 0, stream>>>(qkvb, vtb, yb);

  // out = y @ W_proj^T + b_proj   (M=2048, N=4096, K=4096), fp32 out — 128^2 (fills 512 blocks)
  gemm_bt<0><<<dim3(32, 16), 256, 0, stream>>>(yb, Wpb, b_proj, (void*)out, T, C, C);
}

// Round 3
// 829.617 us; speedup vs baseline: 1.0099x; 1.0099x over previous
//
#include <hip/hip_runtime.h>
#include <cstdint>
#include <cstddef>

typedef __bf16 bf16x8 __attribute__((ext_vector_type(8)));
typedef __bf16 bf16x4 __attribute__((ext_vector_type(4)));
typedef float fx4 __attribute__((ext_vector_type(4)));

static constexpr int T = 2048;
static constexpr int C = 4096;
static constexpr int H = 32;
static constexpr int HS = 128;
static constexpr int QKV_N = 12288; // 3*C

#define MFMA16(a, b, c) __builtin_amdgcn_mfma_f32_16x16x32_bf16((a), (b), (c), 0, 0, 0)

// async global->LDS, 16B per lane. LDS dest = wave-uniform base + lane*16 (m97/m104).
__device__ __forceinline__ void async_cp16(const void* g, void* l) {
  __builtin_amdgcn_global_load_lds((const __attribute__((address_space(1))) unsigned int*)g,
                                   (__attribute__((address_space(3))) unsigned int*)l,
                                   16, 0, 0);
}

// ---------------------------------------------------------------- fp32 -> bf16
__global__ __launch_bounds__(256) void cvt_f32_to_bf16(const float* __restrict__ in,
                                                       __bf16* __restrict__ out, int n4) {
  int i = blockIdx.x * 256 + threadIdx.x;
  if (i >= n4) return;
  float4 v = ((const float4*)in)[i];
  bf16x4 o;
  o.x = (__bf16)v.x; o.y = (__bf16)v.y; o.z = (__bf16)v.z; o.w = (__bf16)v.w;
  ((bf16x4*)out)[i] = o;
}

// ---------------------------------------------------------------- GEMM C = A * B^T + bias (128^2 m97-structure)
// kept for the proj GEMM (only 128 tiles at 256^2 -> half-GPU idle there).
template <int OUT_BF16>
__global__ __launch_bounds__(256, 2) void gemm_bt(const __bf16* __restrict__ A,
                                                  const __bf16* __restrict__ B,
                                                  const float* __restrict__ bias,
                                                  void* __restrict__ Cout,
                                                  int M, int N, int K) {
  constexpr int BM = 128, BN = 128, BK = 64;
  __shared__ __align__(16) __bf16 As[BM * BK]; // 16 KiB, swizzled 16B slots
  __shared__ __align__(16) __bf16 Bs[BN * BK];
  const int tid = threadIdx.x;
  const int lane = tid & 63;
  const int wid = tid >> 6;
  const int wm = (wid >> 1) * 64;
  const int wn = (wid & 1) * 64;
  const int m0 = blockIdx.y * BM;
  const int n0 = blockIdx.x * BN;
  const int lr = lane & 15;   // frag row (A) / col (B,C)
  const int quad = lane >> 4; // k-quad for inputs, row-quad for C

  fx4 acc[4][4] = {};

  for (int k0 = 0; k0 < K; k0 += BK) {
#pragma unroll
    for (int c = 0; c < 4; ++c) {
      int chunk = wid * 4 + c;
      int s = chunk * 64 + lane;
      int r = s >> 3;
      int kc = (s & 7) ^ (r & 7);
      async_cp16(A + (size_t)(m0 + r) * K + k0 + kc * 8, &As[chunk * 512]);
      async_cp16(B + (size_t)(n0 + r) * K + k0 + kc * 8, &Bs[chunk * 512]);
    }
    __syncthreads();
#pragma unroll
    for (int ks = 0; ks < BK; ks += 32) {
      bf16x8 af[4], bfr[4];
#pragma unroll
      for (int mm = 0; mm < 4; ++mm) {
        int r = wm + mm * 16 + lr;
        int kc = (ks >> 3) + quad;
        af[mm] = *(const bf16x8*)(&As[(r * 8 + (kc ^ (r & 7))) * 8]);
      }
#pragma unroll
      for (int nn = 0; nn < 4; ++nn) {
        int r = wn + nn * 16 + lr;
        int kc = (ks >> 3) + quad;
        bfr[nn] = *(const bf16x8*)(&Bs[(r * 8 + (kc ^ (r & 7))) * 8]);
      }
#pragma unroll
      for (int mm = 0; mm < 4; ++mm)
#pragma unroll
        for (int nn = 0; nn < 4; ++nn)
          acc[mm][nn] = MFMA16(af[mm], bfr[nn], acc[mm][nn]);
    }
    __syncthreads();
  }

  // C/D layout (m89/m91 verified): col = lane&15, row = (lane>>4)*4 + reg
#pragma unroll
  for (int nn = 0; nn < 4; ++nn) {
    int col = n0 + wn + nn * 16 + lr;
    float bv = bias[col];
#pragma unroll
    for (int mm = 0; mm < 4; ++mm) {
#pragma unroll
      for (int r = 0; r < 4; ++r) {
        int row = m0 + wm + mm * 16 + quad * 4 + r;
        float v = acc[mm][nn][r] + bv;
        if (OUT_BF16)
          ((__bf16*)Cout)[(size_t)row * N + col] = (__bf16)v;
        else
          ((float*)Cout)[(size_t)row * N + col] = v;
      }
    }
  }
}

// ---------------------------------------------------------------- GEMM 256^2 8-phase (T2+T3+T4+T5+T1)
// C = A * B^T + bias. A:[M,K], B:[N,K] bf16. 512 thr (8 waves, 2Mx4N), BK=64,
// double-buffered 128 KiB LDS. Half-tiles are K-halves (256 rows x 32 cols, 16 KiB).
// Counted vmcnt(6) at phases 4/8 only; never drained to 0 in the main loop.
//
// LDS swizzle (round-1 fix): rows are 4x16B chunks (64B = HALF a bank line), so
// slot8 = 4*(r&1) + (chunk ^ g(r)). g(r)=r&3 collapsed a 16-lane read phase to
// 4 slots x 4 lanes (4-way conflict, 1.89e7 measured). g(r)=(r>>1)&3 gives
// even-lr lanes slots {0..3} x2, odd-lr lanes {4..7} x2 -> 2 lanes/slot = free (m136).
// chunk (r,kc) stored at slot r*4 + (kc ^ ((r>>1)&3)); same involution on read.
__device__ __forceinline__ void stage_half_256(const __bf16* __restrict__ src,
                                               __bf16* lds, int row0, int kcol0,
                                               int K, int tid) {
#pragma unroll
  for (int j2 = 0; j2 < 2; ++j2) {
    int s = j2 * 512 + tid;            // chunk id 0..1023 within the half
    int r = s >> 2;                    // row 0..255
    int kc = (s & 3) ^ ((r >> 1) & 3); // pre-swizzled global chunk
    async_cp16(src + (size_t)(row0 + r) * K + kcol0 + kc * 8,
               lds + (size_t)(j2 * 512 + (tid & 448)) * 8); // wave-uniform base
  }
}

#define GBAR()                                  \
  do {                                          \
    __builtin_amdgcn_sched_barrier(0);          \
    asm volatile("s_barrier" ::: "memory");     \
    __builtin_amdgcn_sched_barrier(0);          \
  } while (0)

// one phase: {ds-read frag subtile; stage-issue; barrier; lgkmcnt(0); setprio+16 MFMA; tail-wait; barrier}
#define PHASE(P, KK, MMB, LOADB, STAGE_STMT, TAILWAIT)                              \
  {                                                                                 \
    const __bf16* Ah = &As[P][KK][0];                                               \
    const __bf16* Bh = &Bs[P][KK][0];                                               \
    bf16x8 af[4];                                                                   \
    _Pragma("unroll") for (int m_ = 0; m_ < 4; ++m_) {                              \
      int r_ = (wr << 7) + (MMB + m_) * 16 + lr;                                    \
      af[m_] = *(const bf16x8*)(Ah + ((r_ << 2) + (quad ^ ((r_ >> 1) & 3))) * 8);   \
    }                                                                               \
    if (LOADB) {                                                                    \
      _Pragma("unroll") for (int n_ = 0; n_ < 4; ++n_) {                            \
        int r_ = (wc << 6) + n_ * 16 + lr;                                          \
        bfr[n_] = *(const bf16x8*)(Bh + ((r_ << 2) + (quad ^ ((r_ >> 1) & 3))) * 8);\
      }                                                                             \
    }                                                                               \
    STAGE_STMT;                                                                     \
    GBAR();                                                                         \
    asm volatile("s_waitcnt lgkmcnt(0)" ::: "memory");                              \
    __builtin_amdgcn_sched_barrier(0);                                              \
    __builtin_amdgcn_s_setprio(1);                                                  \
    _Pragma("unroll") for (int m_ = 0; m_ < 4; ++m_)                                \
      _Pragma("unroll") for (int n_ = 0; n_ < 4; ++n_)                              \
        acc[MMB + m_][n_] = MFMA16(af[m_], bfr[n_], acc[MMB + m_][n_]);             \
    __builtin_amdgcn_s_setprio(0);                                                  \
    TAILWAIT;                                                                       \
    GBAR();                                                                         \
  }

template <int OUT_BF16>
__global__ __launch_bounds__(512, 2) void gemm_bt_256(const __bf16* __restrict__ A,
                                                      const __bf16* __restrict__ B,
                                                      const float* __restrict__ bias,
                                                      void* __restrict__ Cout,
                                                      int M, int N, int K) {
  __shared__ __align__(16) __bf16 As[2][2][8192]; // [buf][khalf][256r x 4chunks x 8] = 64 KiB
  __shared__ __align__(16) __bf16 Bs[2][2][8192]; // 64 KiB
  const int tid = threadIdx.x;
  const int lane = tid & 63;
  const int wid = tid >> 6;
  const int wr = wid >> 2; // 0..1 -> 128-row block
  const int wc = wid & 3;  // 0..3 -> 64-col block
  const int lr = lane & 15;
  const int quad = lane >> 4;

  // T1: bijective XCD-chunked swizzle (nwg % 8 == 0 for our launches)
  int nwg = gridDim.x * gridDim.y;
  int orig = blockIdx.y * gridDim.x + blockIdx.x;
  int swz = orig;
  if ((nwg & 7) == 0) swz = (orig & 7) * (nwg >> 3) + (orig >> 3);
  const int m0 = (swz / gridDim.x) * 256;
  const int n0 = (swz % gridDim.x) * 256;

  fx4 acc[8][4] = {};
  bf16x8 bfr[4];

  const int NT = K >> 6; // 64-wide K tiles (K % 128 == 0)
  const int NPAIR = NT >> 1;

  // prologue: t0 all 4 halves, vmcnt(4); t1 first 3 halves, vmcnt(6)  (m201 recipe)
  stage_half_256(B, &Bs[0][0][0], n0, 0, K, tid);
  stage_half_256(A, &As[0][0][0], m0, 0, K, tid);
  stage_half_256(B, &Bs[0][1][0], n0, 32, K, tid);
  stage_half_256(A, &As[0][1][0], m0, 32, K, tid);
  asm volatile("s_waitcnt vmcnt(4)" ::: "memory");
  stage_half_256(B, &Bs[1][0][0], n0, 64, K, tid);
  stage_half_256(A, &As[1][0][0], m0, 64, K, tid);
  stage_half_256(B, &Bs[1][1][0], n0, 96, K, tid);
  asm volatile("s_waitcnt vmcnt(6)" ::: "memory");
  GBAR();

  // steady state: iteration computes tiles a=2i (buf0, ph1-4) and a+1 (buf1, ph5-8).
  // stage schedule (each target region freed by the previous phase's closing barrier):
  //  ph1:(a+1).A.k1  ph2:(a+2).B.k0  ph3:(a+2).A.k0  ph4:(a+2).B.k1 +vmcnt(6)
  //  ph5:(a+2).A.k1  ph6:(a+3).B.k0  ph7:(a+3).A.k0  ph8:(a+3).B.k1 +vmcnt(6)
  for (int i = 0; i + 1 < NPAIR; ++i) {
    const int k1 = (2 * i + 1) << 6;
    const int k2 = (2 * i + 2) << 6;
    const int k3 = (2 * i + 3) << 6;
    PHASE(0, 0, 0, 1, stage_half_256(A, &As[1][1][0], m0, k1 + 32, K, tid), );
    PHASE(0, 0, 4, 0, stage_half_256(B, &Bs[0][0][0], n0, k2, K, tid), );
    PHASE(0, 1, 0, 1, stage_half_256(A, &As[0][0][0], m0, k2, K, tid), );
    PHASE(0, 1, 4, 0, stage_half_256(B, &Bs[0][1][0], n0, k2 + 32, K, tid),
          asm volatile("s_waitcnt vmcnt(6)" ::: "memory"));
    PHASE(1, 0, 0, 1, stage_half_256(A, &As[0][1][0], m0, k2 + 32, K, tid), );
    PHASE(1, 0, 4, 0, stage_half_256(B, &Bs[1][0][0], n0, k3, K, tid), );
    PHASE(1, 1, 0, 1, stage_half_256(A, &As[1][0][0], m0, k3, K, tid), );
    PHASE(1, 1, 4, 0, stage_half_256(B, &Bs[1][1][0], n0, k3 + 32, K, tid),
          asm volatile("s_waitcnt vmcnt(6)" ::: "memory"));
  }
  // epilogue iteration: tiles NT-2 (buf0), NT-1 (buf1); drain 4 -> 2 -> 0
  {
    const int k1 = (NT - 1) << 6;
    PHASE(0, 0, 0, 1, stage_half_256(A, &As[1][1][0], m0, k1 + 32, K, tid), );
    PHASE(0, 0, 4, 0, , asm volatile("s_waitcnt vmcnt(4)" ::: "memory"));
    PHASE(0, 1, 0, 1, , asm volatile("s_waitcnt vmcnt(2)" ::: "memory"));
    PHASE(0, 1, 4, 0, , asm volatile("s_waitcnt vmcnt(0)" ::: "memory"));
    PHASE(1, 0, 0, 1, , );
    PHASE(1, 0, 4, 0, , );
    PHASE(1, 1, 0, 1, , );
    PHASE(1, 1, 4, 0, , );
  }

  // C/D layout (m89/m91): col = lane&15, row = (lane>>4)*4 + reg
#pragma unroll
  for (int nn = 0; nn < 4; ++nn) {
    int col = n0 + (wc << 6) + nn * 16 + lr;
    float bv = bias[col];
#pragma unroll
    for (int mm = 0; mm < 8; ++mm) {
#pragma unroll
      for (int r = 0; r < 4; ++r) {
        int row = m0 + (wr << 7) + mm * 16 + quad * 4 + r;
        float v = acc[mm][nn][r] + bv;
        if (OUT_BF16)
          ((__bf16*)Cout)[(size_t)row * N + col] = (__bf16)v;
        else
          ((float*)Cout)[(size_t)row * N + col] = v;
      }
    }
  }
}

// ---------------------------------------------------------------- RoPE in-place on qkv (q and k, dims 0..31)
__global__ __launch_bounds__(256) void rope_kernel(__bf16* __restrict__ qkv,
                                                   const float* __restrict__ cosp,
                                                   const float* __restrict__ sinp) {
  int tid = blockIdx.x * 256 + threadIdx.x; // total 2048*32*2*16
  int d = tid & 15;
  int which = (tid >> 4) & 1;
  int h = (tid >> 5) & 31;
  int t = tid >> 10;
  size_t base = (size_t)t * QKV_N + h * 384 + which * 128;
  float x1 = (float)qkv[base + d];
  float x2 = (float)qkv[base + d + 16];
  float c1 = cosp[t * 32 + d], s1 = sinp[t * 32 + d];
  float c2 = cosp[t * 32 + d + 16], s2 = sinp[t * 32 + d + 16];
  qkv[base + d] = (__bf16)(x1 * c1 - x2 * s1);
  qkv[base + d + 16] = (__bf16)(x2 * c2 + x1 * s2);
}

// ---------------------------------------------------------------- V transpose: vt[h][d][t] = v[h][t][d]
__global__ __launch_bounds__(256) void vtrans_kernel(const __bf16* __restrict__ qkv,
                                                     __bf16* __restrict__ vt) {
  __shared__ __align__(16) __bf16 tile[64][136];
  int h = blockIdx.x;
  int t0 = blockIdx.y * 64;
  int tid = threadIdx.x;
#pragma unroll
  for (int c = 0; c < 4; ++c) {
    int i = tid + c * 256;
    int tl = i >> 4;
    int dp = (i & 15) * 8;
    *(uint4*)(&tile[tl][dp]) = *(const uint4*)(qkv + (size_t)(t0 + tl) * QKV_N + h * 384 + 256 + dp);
  }
  __syncthreads();
#pragma unroll
  for (int c = 0; c < 4; ++c) {
    int o = tid + c * 256;   // 0..1023
    int d = o >> 3;          // 0..127
    int ts = (o & 7) * 8;    // t segment
    bf16x8 v;
#pragma unroll
    for (int j = 0; j < 8; ++j) v[j] = tile[ts + j][d];
    *(bf16x8*)(vt + ((size_t)h * 128 + d) * T + t0 + ts) = v;
  }
}

// ---------------------------------------------------------------- flash-style causal attention, NO-MAX softmax
__global__ __launch_bounds__(256, 2) void attn_kernel(const __bf16* __restrict__ qkv,
                                                      const __bf16* __restrict__ vt,
                                                      __bf16* __restrict__ y) {
  constexpr int KT = 64;
  constexpr int LPS = KT + 8; // 72
  __shared__ __align__(16) __bf16 Ks[KT * HS];  // 16 KiB swizzled
  __shared__ __align__(16) __bf16 Vs[HS * KT];  // 16 KiB swizzled
  __shared__ __align__(16) __bf16 Ps[4][16 * LPS];

  const int h = blockIdx.x;
  const int qb = blockIdx.y;
  const int q0 = qb * 64;
  const int tid = threadIdx.x;
  const int lane = tid & 63;
  const int wid = tid >> 6;
  const int lr = lane & 15;
  const int quad = lane >> 4;
  const int qrow = q0 + wid * 16;

  bf16x8 qf[4];
#pragma unroll
  for (int kk = 0; kk < 4; ++kk)
    qf[kk] = *(const bf16x8*)(qkv + (size_t)(qrow + lr) * QKV_N + h * 384 + kk * 32 + quad * 8);

  float lsum[4];
  fx4 acc_o[8];
#pragma unroll
  for (int r = 0; r < 4; ++r) lsum[r] = 0.f;
#pragma unroll
  for (int dd = 0; dd < 8; ++dd) acc_o[dd] = (fx4)0.f;

  const float c_e2 = 0.08838834764831845f * 1.4426950408889634f;
  const int ntiles = qb + 1;
  for (int kt = 0; kt < ntiles; ++kt) {
    const int kbase = kt * KT;
#pragma unroll
    for (int c = 0; c < 4; ++c) {
      int chunk = wid * 4 + c;
      int s = chunk * 64 + lane;
      int r = s >> 4;
      int kc = (s & 15) ^ (r & 15);
      async_cp16(qkv + (size_t)(kbase + r) * QKV_N + h * 384 + 128 + kc * 8, &Ks[chunk * 512]);
    }
#pragma unroll
    for (int c = 0; c < 4; ++c) {
      int chunk = wid * 4 + c;
      int s = chunk * 64 + lane;
      int r = s >> 3;
      int kc = (s & 7) ^ (r & 7);
      async_cp16(vt + ((size_t)h * 128 + r) * T + kbase + kc * 8, &Vs[chunk * 512]);
    }
    __syncthreads();

    fx4 sv[4] = {};
#pragma unroll
    for (int nn = 0; nn < 4; ++nn) {
#pragma unroll
      for (int kk = 0; kk < 4; ++kk) {
        int r = nn * 16 + lr;
        int kc = kk * 4 + quad;
        bf16x8 kf = *(const bf16x8*)(&Ks[(r * 16 + (kc ^ (r & 15))) * 8]);
        sv[nn] = MFMA16(qf[kk], kf, sv[nn]);
      }
    }

#pragma unroll
    for (int nn = 0; nn < 4; ++nn) {
      int kj = kbase + nn * 16 + lr;
#pragma unroll
      for (int r = 0; r < 4; ++r) {
        int qi = qrow + quad * 4 + r;
        float p = __builtin_amdgcn_exp2f(sv[nn][r] * c_e2);
        p = (kj > qi) ? 0.f : p;
        lsum[r] += p;
        Ps[wid][(quad * 4 + r) * LPS + nn * 16 + lr] = (__bf16)p;
      }
    }
    asm volatile("s_waitcnt lgkmcnt(0)" ::: "memory");

#pragma unroll
    for (int kc0 = 0; kc0 < 2; ++kc0) {
      bf16x8 pf = *(const bf16x8*)(&Ps[wid][lr * LPS + kc0 * 32 + quad * 8]);
#pragma unroll
      for (int dd = 0; dd < 8; ++dd) {
        int r = dd * 16 + lr;
        int kc = kc0 * 4 + quad;
        bf16x8 vf = *(const bf16x8*)(&Vs[(r * 8 + (kc ^ (r & 7))) * 8]);
        acc_o[dd] = MFMA16(pf, vf, acc_o[dd]);
      }
    }
    __syncthreads();
  }

#pragma unroll
  for (int off = 1; off < 16; off <<= 1)
#pragma unroll
    for (int r = 0; r < 4; ++r)
      lsum[r] += __shfl_xor(lsum[r], off, 64);
#pragma unroll
  for (int r = 0; r < 4; ++r) lsum[r] = 1.0f / lsum[r];

#pragma unroll
  for (int dd = 0; dd < 8; ++dd)
#pragma unroll
    for (int r = 0; r < 4; ++r) {
      int row = qrow + quad * 4 + r;
      int col = h * 128 + dd * 16 + lr;
      y[(size_t)row * C + col] = (__bf16)(acc_o[dd][r] * lsum[r]);
    }
}

// ---------------------------------------------------------------- launcher
extern "C" void kernel_launch(void* const* d_in, const int* in_sizes, int n_in,
                              void* d_out, int out_size, void* d_ws, size_t ws_size,
                              hipStream_t stream) {
  const float* x      = (const float*)d_in[0];
  const float* cosp   = (const float*)d_in[1];
  const float* sinp   = (const float*)d_in[2];
  const float* W_attn = (const float*)d_in[3];
  const float* b_attn = (const float*)d_in[4];
  const float* W_proj = (const float*)d_in[5];
  const float* b_proj = (const float*)d_in[6];
  float* out = (float*)d_out;

  char* wsb = (char*)d_ws;
  __bf16* Wab  = (__bf16*)(wsb + 0);          // 12288*4096*2 = 100663296
  __bf16* Wpb  = (__bf16*)(wsb + 100663296);  // 4096*4096*2  =  33554432
  __bf16* xb   = (__bf16*)(wsb + 134217728);  // 2048*4096*2  =  16777216
  __bf16* qkvb = (__bf16*)(wsb + 150994944);  // 2048*12288*2 =  50331648
  __bf16* yb   = (__bf16*)(wsb + 201326592);  // 2048*4096*2  =  16777216
  __bf16* vtb  = (__bf16*)(wsb + 218103808);  // 32*128*2048*2=  16777216

  cvt_f32_to_bf16<<<8192, 256, 0, stream>>>(x, xb, (T * C) / 4);
  cvt_f32_to_bf16<<<49152, 256, 0, stream>>>(W_attn, Wab, (QKV_N * C) / 4);
  cvt_f32_to_bf16<<<16384, 256, 0, stream>>>(W_proj, Wpb, (C * C) / 4);

  // qkv = x @ W_attn^T + b_attn   (M=2048, N=12288, K=4096) — 256^2 8-phase
  gemm_bt_256<1><<<dim3(48, 8), 512, 0, stream>>>(xb, Wab, b_attn, (void*)qkvb, T, QKV_N, C);

  rope_kernel<<<8192, 256, 0, stream>>>(qkvb, cosp, sinp);
  vtrans_kernel<<<dim3(32, 32), 256, 0, stream>>>(qkvb, vtb);

  attn_kernel<<<dim3(32, 32), 256, 0, stream>>>(qkvb, vtb, yb);

  // out = y @ W_proj^T + b_proj   (M=2048, N=4096, K=4096), fp32 out — 128^2 (fills 512 blocks)
  gemm_bt<0><<<dim3(32, 16), 256, 0, stream>>>(yb, Wpb, b_proj, (void*)out, T, C, C);
}

// Round 4
// 733.396 us; speedup vs baseline: 1.1424x; 1.1312x over previous
//
#include <hip/hip_runtime.h>
#include <cstdint>
#include <cstddef>

typedef __bf16 bf16x8 __attribute__((ext_vector_type(8)));
typedef __bf16 bf16x4 __attribute__((ext_vector_type(4)));
typedef float fx4 __attribute__((ext_vector_type(4)));

static constexpr int T = 2048;
static constexpr int C = 4096;
static constexpr int H = 32;
static constexpr int HS = 128;
static constexpr int QKV_N = 12288; // 3*C

#define MFMA16(a, b, c) __builtin_amdgcn_mfma_f32_16x16x32_bf16((a), (b), (c), 0, 0, 0)

// async global->LDS, 16B per lane. LDS dest = wave-uniform base + lane*16 (m97/m104).
__device__ __forceinline__ void async_cp16(const void* g, void* l) {
  __builtin_amdgcn_global_load_lds((const __attribute__((address_space(1))) unsigned int*)g,
                                   (__attribute__((address_space(3))) unsigned int*)l,
                                   16, 0, 0);
}

// ---------------------------------------------------------------- fp32 -> bf16
__global__ __launch_bounds__(256) void cvt_f32_to_bf16(const float* __restrict__ in,
                                                       __bf16* __restrict__ out, int n4) {
  int i = blockIdx.x * 256 + threadIdx.x;
  if (i >= n4) return;
  float4 v = ((const float4*)in)[i];
  bf16x4 o;
  o.x = (__bf16)v.x; o.y = (__bf16)v.y; o.z = (__bf16)v.z; o.w = (__bf16)v.w;
  ((bf16x4*)out)[i] = o;
}

// ---------------------------------------------------------------- GEMM C = A * B^T + bias
// A: [M,K] bf16 row-major; B: [N,K] bf16 row-major; bias: [N] f32.
// 128x128 tile, BK=64, 4 waves in 2x2 of 64x64. Measured: 216us qkv, MfmaUtil 43,
// SQ_LDS_BANK_CONFLICT 0. (256^2 8-phase port tried rounds 1-3: 313us best — reverted.)
template <int OUT_BF16>
__global__ __launch_bounds__(256, 2) void gemm_bt(const __bf16* __restrict__ A,
                                                  const __bf16* __restrict__ B,
                                                  const float* __restrict__ bias,
                                                  void* __restrict__ Cout,
                                                  int M, int N, int K) {
  constexpr int BM = 128, BN = 128, BK = 64;
  __shared__ __align__(16) __bf16 As[BM * BK]; // 16 KiB, swizzled 16B slots
  __shared__ __align__(16) __bf16 Bs[BN * BK];
  const int tid = threadIdx.x;
  const int lane = tid & 63;
  const int wid = tid >> 6;
  const int wm = (wid >> 1) * 64;
  const int wn = (wid & 1) * 64;
  const int m0 = blockIdx.y * BM;
  const int n0 = blockIdx.x * BN;
  const int lr = lane & 15;   // frag row (A) / col (B,C)
  const int quad = lane >> 4; // k-quad for inputs, row-quad for C

  fx4 acc[4][4] = {};

  for (int k0 = 0; k0 < K; k0 += BK) {
#pragma unroll
    for (int c = 0; c < 4; ++c) {
      int chunk = wid * 4 + c;
      int s = chunk * 64 + lane;
      int r = s >> 3;
      int kc = (s & 7) ^ (r & 7);
      async_cp16(A + (size_t)(m0 + r) * K + k0 + kc * 8, &As[chunk * 512]);
      async_cp16(B + (size_t)(n0 + r) * K + k0 + kc * 8, &Bs[chunk * 512]);
    }
    __syncthreads();
#pragma unroll
    for (int ks = 0; ks < BK; ks += 32) {
      bf16x8 af[4], bfr[4];
#pragma unroll
      for (int mm = 0; mm < 4; ++mm) {
        int r = wm + mm * 16 + lr;
        int kc = (ks >> 3) + quad;
        af[mm] = *(const bf16x8*)(&As[(r * 8 + (kc ^ (r & 7))) * 8]);
      }
#pragma unroll
      for (int nn = 0; nn < 4; ++nn) {
        int r = wn + nn * 16 + lr;
        int kc = (ks >> 3) + quad;
        bfr[nn] = *(const bf16x8*)(&Bs[(r * 8 + (kc ^ (r & 7))) * 8]);
      }
#pragma unroll
      for (int mm = 0; mm < 4; ++mm)
#pragma unroll
        for (int nn = 0; nn < 4; ++nn)
          acc[mm][nn] = MFMA16(af[mm], bfr[nn], acc[mm][nn]);
    }
    __syncthreads();
  }

  // C/D layout (m89/m91 verified): col = lane&15, row = (lane>>4)*4 + reg
#pragma unroll
  for (int nn = 0; nn < 4; ++nn) {
    int col = n0 + wn + nn * 16 + lr;
    float bv = bias[col];
#pragma unroll
    for (int mm = 0; mm < 4; ++mm) {
#pragma unroll
      for (int r = 0; r < 4; ++r) {
        int row = m0 + wm + mm * 16 + quad * 4 + r;
        float v = acc[mm][nn][r] + bv;
        if (OUT_BF16)
          ((__bf16*)Cout)[(size_t)row * N + col] = (__bf16)v;
        else
          ((float*)Cout)[(size_t)row * N + col] = v;
      }
    }
  }
}

// ---------------------------------------------------------------- RoPE in-place on qkv (q and k, dims 0..31)
__global__ __launch_bounds__(256) void rope_kernel(__bf16* __restrict__ qkv,
                                                   const float* __restrict__ cosp,
                                                   const float* __restrict__ sinp) {
  int tid = blockIdx.x * 256 + threadIdx.x; // total 2048*32*2*16
  int d = tid & 15;
  int which = (tid >> 4) & 1;
  int h = (tid >> 5) & 31;
  int t = tid >> 10;
  size_t base = (size_t)t * QKV_N + h * 384 + which * 128;
  float x1 = (float)qkv[base + d];
  float x2 = (float)qkv[base + d + 16];
  float c1 = cosp[t * 32 + d], s1 = sinp[t * 32 + d];
  float c2 = cosp[t * 32 + d + 16], s2 = sinp[t * 32 + d + 16];
  qkv[base + d] = (__bf16)(x1 * c1 - x2 * s1);
  qkv[base + d + 16] = (__bf16)(x2 * c2 + x1 * s2);
}

// ---------------------------------------------------------------- V transpose: vt[h][d][t] = v[h][t][d]
__global__ __launch_bounds__(256) void vtrans_kernel(const __bf16* __restrict__ qkv,
                                                     __bf16* __restrict__ vt) {
  __shared__ __align__(16) __bf16 tile[64][136];
  int h = blockIdx.x;
  int t0 = blockIdx.y * 64;
  int tid = threadIdx.x;
#pragma unroll
  for (int c = 0; c < 4; ++c) {
    int i = tid + c * 256;
    int tl = i >> 4;
    int dp = (i & 15) * 8;
    *(uint4*)(&tile[tl][dp]) = *(const uint4*)(qkv + (size_t)(t0 + tl) * QKV_N + h * 384 + 256 + dp);
  }
  __syncthreads();
#pragma unroll
  for (int c = 0; c < 4; ++c) {
    int o = tid + c * 256;   // 0..1023
    int d = o >> 3;          // 0..127
    int ts = (o & 7) * 8;    // t segment
    bf16x8 v;
#pragma unroll
    for (int j = 0; j < 8; ++j) v[j] = tile[ts + j][d];
    *(bf16x8*)(vt + ((size_t)h * 128 + d) * T + t0 + ts) = v;
  }
}

// ---------------------------------------------------------------- flash-style causal attention, NO-MAX softmax
// Round-3 change: DOUBLE-BUFFERED K/V staging with counted vmcnt (T3-minimum).
// Old: stage -> __syncthreads (= vmcnt(0) drain) every tile => full HBM/L2 latency
// stall per tile. New: issue tile t+1's 8 global_load_lds BEFORE computing tile t;
// raw s_barrier + s_waitcnt vmcnt(8) keeps the 8 prefetch loads in flight across
// the barrier; they land under QK->softmax->PV. LDS 73 KiB -> still 2 blocks/CU.
__global__ __launch_bounds__(256, 2) void attn_kernel(const __bf16* __restrict__ qkv,
                                                      const __bf16* __restrict__ vt,
                                                      __bf16* __restrict__ y) {
  constexpr int KT = 64;
  constexpr int LPS = KT + 8; // 72
  __shared__ __align__(16) __bf16 Ks[2][KT * HS];  // 2 x 16 KiB swizzled
  __shared__ __align__(16) __bf16 Vs[2][HS * KT];  // 2 x 16 KiB swizzled
  __shared__ __align__(16) __bf16 Ps[4][16 * LPS];

  const int h = blockIdx.x;
  const int qb = blockIdx.y;
  const int q0 = qb * 64;
  const int tid = threadIdx.x;
  const int lane = tid & 63;
  const int wid = tid >> 6;
  const int lr = lane & 15;
  const int quad = lane >> 4;
  const int qrow = q0 + wid * 16;

  // Q A-frags in registers: A[m=lr][k=quad*8+j], 4 chunks over d=128
  bf16x8 qf[4];
#pragma unroll
  for (int kk = 0; kk < 4; ++kk)
    qf[kk] = *(const bf16x8*)(qkv + (size_t)(qrow + lr) * QKV_N + h * 384 + kk * 32 + quad * 8);

  float lsum[4];  // per-lane partial row sums (row = quad*4+r)
  fx4 acc_o[8];
#pragma unroll
  for (int r = 0; r < 4; ++r) lsum[r] = 0.f;
#pragma unroll
  for (int dd = 0; dd < 8; ++dd) acc_o[dd] = (fx4)0.f;

  // exp(s*scale) = exp2(s * scale*log2e)
  const float c_e2 = 0.08838834764831845f * 1.4426950408889634f;
  const int ntiles = qb + 1;

  // 8 global_load_lds per thread per stage (4 K + 4 V)
  auto stage = [&](int kt, int buf) {
    const int kbase = kt * KT;
#pragma unroll
    for (int c = 0; c < 4; ++c) {
      int chunk = wid * 4 + c;
      int s = chunk * 64 + lane;
      int r = s >> 4;
      int kc = (s & 15) ^ (r & 15);
      async_cp16(qkv + (size_t)(kbase + r) * QKV_N + h * 384 + 128 + kc * 8,
                 &Ks[buf][chunk * 512]);
    }
#pragma unroll
    for (int c = 0; c < 4; ++c) {
      int chunk = wid * 4 + c;
      int s = chunk * 64 + lane;
      int r = s >> 3;
      int kc = (s & 7) ^ (r & 7);
      async_cp16(vt + ((size_t)h * 128 + r) * T + kbase + kc * 8,
                 &Vs[buf][chunk * 512]);
    }
  };

  auto compute = [&](int kt, int buf) {
    const int kbase = kt * KT;
    // S = Q K^T (16 x 64 per wave)
    fx4 sv[4] = {};
#pragma unroll
    for (int nn = 0; nn < 4; ++nn) {
#pragma unroll
      for (int kk = 0; kk < 4; ++kk) {
        int r = nn * 16 + lr;
        int kc = kk * 4 + quad;
        bf16x8 kf = *(const bf16x8*)(&Ks[buf][(r * 16 + (kc ^ (r & 15))) * 8]);
        sv[nn] = MFMA16(qf[kk], kf, sv[nn]);
      }
    }

    // p = exp2(s*c), masked to 0 beyond causal; per-lane row sums; P -> LDS (A-layout)
#pragma unroll
    for (int nn = 0; nn < 4; ++nn) {
      int kj = kbase + nn * 16 + lr;
#pragma unroll
      for (int r = 0; r < 4; ++r) {
        int qi = qrow + quad * 4 + r;
        float p = __builtin_amdgcn_exp2f(sv[nn][r] * c_e2); // v_exp_f32
        p = (kj > qi) ? 0.f : p;
        lsum[r] += p;
        Ps[wid][(quad * 4 + r) * LPS + nn * 16 + lr] = (__bf16)p;
      }
    }
    asm volatile("s_waitcnt lgkmcnt(0)" ::: "memory");

    // O += P @ V : A = P[m=qi][k=kj], B = Vs[n=d][k=kj]
#pragma unroll
    for (int kc0 = 0; kc0 < 2; ++kc0) {
      bf16x8 pf = *(const bf16x8*)(&Ps[wid][lr * LPS + kc0 * 32 + quad * 8]);
#pragma unroll
      for (int dd = 0; dd < 8; ++dd) {
        int r = dd * 16 + lr;
        int kc = kc0 * 4 + quad;
        bf16x8 vf = *(const bf16x8*)(&Vs[buf][(r * 8 + (kc ^ (r & 7))) * 8]);
        acc_o[dd] = MFMA16(pf, vf, acc_o[dd]);
      }
    }
  };

  // prologue
  stage(0, 0);
  int cur = 0;
  // steady state: prefetch t+1, counted-wait for t, compute t
  for (int kt = 0; kt < ntiles - 1; ++kt) {
    stage(kt + 1, cur ^ 1);
    asm volatile("s_waitcnt vmcnt(8)" ::: "memory"); // own 8 loads of buf[cur] done
    __builtin_amdgcn_sched_barrier(0);
    __builtin_amdgcn_s_barrier();                    // all waves' parts of buf[cur] visible
    __builtin_amdgcn_sched_barrier(0);
    compute(kt, cur);
    __builtin_amdgcn_sched_barrier(0);
    __builtin_amdgcn_s_barrier();                    // protect buf[cur] before restage next iter
    __builtin_amdgcn_sched_barrier(0);
    cur ^= 1;
  }
  // last tile: full drain
  asm volatile("s_waitcnt vmcnt(0)" ::: "memory");
  __builtin_amdgcn_sched_barrier(0);
  __builtin_amdgcn_s_barrier();
  __builtin_amdgcn_sched_barrier(0);
  compute(ntiles - 1, cur);

  // one reduction of row sums across the quad's 16 lanes
#pragma unroll
  for (int off = 1; off < 16; off <<= 1)
#pragma unroll
    for (int r = 0; r < 4; ++r)
      lsum[r] += __shfl_xor(lsum[r], off, 64);
#pragma unroll
  for (int r = 0; r < 4; ++r) lsum[r] = 1.0f / lsum[r];

#pragma unroll
  for (int dd = 0; dd < 8; ++dd)
#pragma unroll
    for (int r = 0; r < 4; ++r) {
      int row = qrow + quad * 4 + r;
      int col = h * 128 + dd * 16 + lr;
      y[(size_t)row * C + col] = (__bf16)(acc_o[dd][r] * lsum[r]);
    }
}

// ---------------------------------------------------------------- launcher
extern "C" void kernel_launch(void* const* d_in, const int* in_sizes, int n_in,
                              void* d_out, int out_size, void* d_ws, size_t ws_size,
                              hipStream_t stream) {
  const float* x      = (const float*)d_in[0];
  const float* cosp   = (const float*)d_in[1];
  const float* sinp   = (const float*)d_in[2];
  const float* W_attn = (const float*)d_in[3];
  const float* b_attn = (const float*)d_in[4];
  const float* W_proj = (const float*)d_in[5];
  const float* b_proj = (const float*)d_in[6];
  float* out = (float*)d_out;

  // workspace layout (bytes), all 16B aligned; total 234,881,024
  char* wsb = (char*)d_ws;
  __bf16* Wab  = (__bf16*)(wsb + 0);          // 12288*4096*2 = 100663296
  __bf16* Wpb  = (__bf16*)(wsb + 100663296);  // 4096*4096*2  =  33554432
  __bf16* xb   = (__bf16*)(wsb + 134217728);  // 2048*4096*2  =  16777216
  __bf16* qkvb = (__bf16*)(wsb + 150994944);  // 2048*12288*2 =  50331648
  __bf16* yb   = (__bf16*)(wsb + 201326592);  // 2048*4096*2  =  16777216
  __bf16* vtb  = (__bf16*)(wsb + 218103808);  // 32*128*2048*2=  16777216

  cvt_f32_to_bf16<<<8192, 256, 0, stream>>>(x, xb, (T * C) / 4);
  cvt_f32_to_bf16<<<49152, 256, 0, stream>>>(W_attn, Wab, (QKV_N * C) / 4);
  cvt_f32_to_bf16<<<16384, 256, 0, stream>>>(W_proj, Wpb, (C * C) / 4);

  // qkv = x @ W_attn^T + b_attn   (M=2048, N=12288, K=4096)
  gemm_bt<1><<<dim3(96, 16), 256, 0, stream>>>(xb, Wab, b_attn, (void*)qkvb, T, QKV_N, C);

  rope_kernel<<<8192, 256, 0, stream>>>(qkvb, cosp, sinp);
  vtrans_kernel<<<dim3(32, 32), 256, 0, stream>>>(qkvb, vtb);

  attn_kernel<<<dim3(32, 32), 256, 0, stream>>>(qkvb, vtb, yb);

  // out = y @ W_proj^T + b_proj   (M=2048, N=4096, K=4096), fp32 out
  gemm_bt<0><<<dim3(32, 16), 256, 0, stream>>>(yb, Wpb, b_proj, (void*)out, T, C, C);
}

// Round 5
// 728.091 us; speedup vs baseline: 1.1507x; 1.0073x over previous
//
#include <hip/hip_runtime.h>
#include <cstdint>
#include <cstddef>

typedef __bf16 bf16x8 __attribute__((ext_vector_type(8)));
typedef __bf16 bf16x4 __attribute__((ext_vector_type(4)));
typedef float fx4 __attribute__((ext_vector_type(4)));

static constexpr int T = 2048;
static constexpr int C = 4096;
static constexpr int H = 32;
static constexpr int HS = 128;
static constexpr int QKV_N = 12288; // 3*C

#define MFMA16(a, b, c) __builtin_amdgcn_mfma_f32_16x16x32_bf16((a), (b), (c), 0, 0, 0)

// async global->LDS, 16B per lane. LDS dest = wave-uniform base + lane*16 (m97/m104).
__device__ __forceinline__ void async_cp16(const void* g, void* l) {
  __builtin_amdgcn_global_load_lds((const __attribute__((address_space(1))) unsigned int*)g,
                                   (__attribute__((address_space(3))) unsigned int*)l,
                                   16, 0, 0);
}

// ---------------------------------------------------------------- fp32 -> bf16
__global__ __launch_bounds__(256) void cvt_f32_to_bf16(const float* __restrict__ in,
                                                       __bf16* __restrict__ out, int n4) {
  int i = blockIdx.x * 256 + threadIdx.x;
  if (i >= n4) return;
  float4 v = ((const float4*)in)[i];
  bf16x4 o;
  o.x = (__bf16)v.x; o.y = (__bf16)v.y; o.z = (__bf16)v.z; o.w = (__bf16)v.w;
  ((bf16x4*)out)[i] = o;
}

// ---------------------------------------------------------------- GEMM C = A * B^T + bias
// A: [M,K] bf16 row-major; B: [N,K] bf16 row-major; bias: [N] f32.
// 128x128 tile, BK=64, 4 waves in 2x2 of 64x64. Measured: 216us qkv, MfmaUtil 43,
// SQ_LDS_BANK_CONFLICT 0. (256^2 8-phase port tried rounds 1-3: 313us best — reverted.)
template <int OUT_BF16>
__global__ __launch_bounds__(256, 2) void gemm_bt(const __bf16* __restrict__ A,
                                                  const __bf16* __restrict__ B,
                                                  const float* __restrict__ bias,
                                                  void* __restrict__ Cout,
                                                  int M, int N, int K) {
  constexpr int BM = 128, BN = 128, BK = 64;
  __shared__ __align__(16) __bf16 As[BM * BK]; // 16 KiB, swizzled 16B slots
  __shared__ __align__(16) __bf16 Bs[BN * BK];
  const int tid = threadIdx.x;
  const int lane = tid & 63;
  const int wid = tid >> 6;
  const int wm = (wid >> 1) * 64;
  const int wn = (wid & 1) * 64;
  const int m0 = blockIdx.y * BM;
  const int n0 = blockIdx.x * BN;
  const int lr = lane & 15;   // frag row (A) / col (B,C)
  const int quad = lane >> 4; // k-quad for inputs, row-quad for C

  fx4 acc[4][4] = {};

  for (int k0 = 0; k0 < K; k0 += BK) {
#pragma unroll
    for (int c = 0; c < 4; ++c) {
      int chunk = wid * 4 + c;
      int s = chunk * 64 + lane;
      int r = s >> 3;
      int kc = (s & 7) ^ (r & 7);
      async_cp16(A + (size_t)(m0 + r) * K + k0 + kc * 8, &As[chunk * 512]);
      async_cp16(B + (size_t)(n0 + r) * K + k0 + kc * 8, &Bs[chunk * 512]);
    }
    __syncthreads();
#pragma unroll
    for (int ks = 0; ks < BK; ks += 32) {
      bf16x8 af[4], bfr[4];
#pragma unroll
      for (int mm = 0; mm < 4; ++mm) {
        int r = wm + mm * 16 + lr;
        int kc = (ks >> 3) + quad;
        af[mm] = *(const bf16x8*)(&As[(r * 8 + (kc ^ (r & 7))) * 8]);
      }
#pragma unroll
      for (int nn = 0; nn < 4; ++nn) {
        int r = wn + nn * 16 + lr;
        int kc = (ks >> 3) + quad;
        bfr[nn] = *(const bf16x8*)(&Bs[(r * 8 + (kc ^ (r & 7))) * 8]);
      }
#pragma unroll
      for (int mm = 0; mm < 4; ++mm)
#pragma unroll
        for (int nn = 0; nn < 4; ++nn)
          acc[mm][nn] = MFMA16(af[mm], bfr[nn], acc[mm][nn]);
    }
    __syncthreads();
  }

  // C/D layout (m89/m91 verified): col = lane&15, row = (lane>>4)*4 + reg
#pragma unroll
  for (int nn = 0; nn < 4; ++nn) {
    int col = n0 + wn + nn * 16 + lr;
    float bv = bias[col];
#pragma unroll
    for (int mm = 0; mm < 4; ++mm) {
#pragma unroll
      for (int r = 0; r < 4; ++r) {
        int row = m0 + wm + mm * 16 + quad * 4 + r;
        float v = acc[mm][nn][r] + bv;
        if (OUT_BF16)
          ((__bf16*)Cout)[(size_t)row * N + col] = (__bf16)v;
        else
          ((float*)Cout)[(size_t)row * N + col] = v;
      }
    }
  }
}

// ---------------------------------------------------------------- RoPE in-place on qkv (q and k, dims 0..31)
__global__ __launch_bounds__(256) void rope_kernel(__bf16* __restrict__ qkv,
                                                   const float* __restrict__ cosp,
                                                   const float* __restrict__ sinp) {
  int tid = blockIdx.x * 256 + threadIdx.x; // total 2048*32*2*16
  int d = tid & 15;
  int which = (tid >> 4) & 1;
  int h = (tid >> 5) & 31;
  int t = tid >> 10;
  size_t base = (size_t)t * QKV_N + h * 384 + which * 128;
  float x1 = (float)qkv[base + d];
  float x2 = (float)qkv[base + d + 16];
  float c1 = cosp[t * 32 + d], s1 = sinp[t * 32 + d];
  float c2 = cosp[t * 32 + d + 16], s2 = sinp[t * 32 + d + 16];
  qkv[base + d] = (__bf16)(x1 * c1 - x2 * s1);
  qkv[base + d + 16] = (__bf16)(x2 * c2 + x1 * s2);
}

// ---------------------------------------------------------------- V transpose: vt[h][d][t] = v[h][t][d]
__global__ __launch_bounds__(256) void vtrans_kernel(const __bf16* __restrict__ qkv,
                                                     __bf16* __restrict__ vt) {
  __shared__ __align__(16) __bf16 tile[64][136];
  int h = blockIdx.x;
  int t0 = blockIdx.y * 64;
  int tid = threadIdx.x;
#pragma unroll
  for (int c = 0; c < 4; ++c) {
    int i = tid + c * 256;
    int tl = i >> 4;
    int dp = (i & 15) * 8;
    *(uint4*)(&tile[tl][dp]) = *(const uint4*)(qkv + (size_t)(t0 + tl) * QKV_N + h * 384 + 256 + dp);
  }
  __syncthreads();
#pragma unroll
  for (int c = 0; c < 4; ++c) {
    int o = tid + c * 256;   // 0..1023
    int d = o >> 3;          // 0..127
    int ts = (o & 7) * 8;    // t segment
    bf16x8 v;
#pragma unroll
    for (int j = 0; j < 8; ++j) v[j] = tile[ts + j][d];
    *(bf16x8*)(vt + ((size_t)h * 128 + d) * T + t0 + ts) = v;
  }
}

// ---------------------------------------------------------------- flash-style causal attention, NO-MAX softmax
// Round-4: double-buffered K/V staging, counted vmcnt(8) across raw s_barrier.
// Round-5: COMPLEMENTARY-PAIR blocks for causal load balance. Old grid (32h x 32qb)
// = 1024 blocks on 512 resident slots with work = qb+1 tiles; qb-ascending dispatch
// ran all short blocks first, long blocks second -> makespan ~48 tile-times vs 33
// ideal (tail >90% idle). New: 512 blocks (32h x 16pair); each block processes
// qb=pair AND qb=31-pair => exactly 33 tile-units per block, all blocks resident
// from t=0, balance independent of dispatch order / XCD assignment.
__global__ __launch_bounds__(256, 2) void attn_kernel(const __bf16* __restrict__ qkv,
                                                      const __bf16* __restrict__ vt,
                                                      __bf16* __restrict__ y) {
  constexpr int KT = 64;
  constexpr int LPS = KT + 8; // 72
  __shared__ __align__(16) __bf16 Ks[2][KT * HS];  // 2 x 16 KiB swizzled
  __shared__ __align__(16) __bf16 Vs[2][HS * KT];  // 2 x 16 KiB swizzled
  __shared__ __align__(16) __bf16 Ps[4][16 * LPS];

  const int h = blockIdx.x;
  const int pairIdx = blockIdx.y; // 0..15
  const int tid = threadIdx.x;
  const int lane = tid & 63;
  const int wid = tid >> 6;
  const int lr = lane & 15;
  const int quad = lane >> 4;

  const float c_e2 = 0.08838834764831845f * 1.4426950408889634f; // scale*log2e

  for (int half = 0; half < 2; ++half) {
    const int qb = half ? (31 - pairIdx) : pairIdx;
    const int q0 = qb * 64;
    const int qrow = q0 + wid * 16;

    // Q A-frags in registers: A[m=lr][k=quad*8+j], 4 chunks over d=128
    bf16x8 qf[4];
#pragma unroll
    for (int kk = 0; kk < 4; ++kk)
      qf[kk] = *(const bf16x8*)(qkv + (size_t)(qrow + lr) * QKV_N + h * 384 + kk * 32 + quad * 8);

    float lsum[4];  // per-lane partial row sums (row = quad*4+r)
    fx4 acc_o[8];
#pragma unroll
    for (int r = 0; r < 4; ++r) lsum[r] = 0.f;
#pragma unroll
    for (int dd = 0; dd < 8; ++dd) acc_o[dd] = (fx4)0.f;

    const int ntiles = qb + 1;

    // 8 global_load_lds per thread per stage (4 K + 4 V)
    auto stage = [&](int kt, int buf) {
      const int kbase = kt * KT;
#pragma unroll
      for (int c = 0; c < 4; ++c) {
        int chunk = wid * 4 + c;
        int s = chunk * 64 + lane;
        int r = s >> 4;
        int kc = (s & 15) ^ (r & 15);
        async_cp16(qkv + (size_t)(kbase + r) * QKV_N + h * 384 + 128 + kc * 8,
                   &Ks[buf][chunk * 512]);
      }
#pragma unroll
      for (int c = 0; c < 4; ++c) {
        int chunk = wid * 4 + c;
        int s = chunk * 64 + lane;
        int r = s >> 3;
        int kc = (s & 7) ^ (r & 7);
        async_cp16(vt + ((size_t)h * 128 + r) * T + kbase + kc * 8,
                   &Vs[buf][chunk * 512]);
      }
    };

    auto compute = [&](int kt, int buf) {
      const int kbase = kt * KT;
      // S = Q K^T (16 x 64 per wave)
      fx4 sv[4] = {};
#pragma unroll
      for (int nn = 0; nn < 4; ++nn) {
#pragma unroll
        for (int kk = 0; kk < 4; ++kk) {
          int r = nn * 16 + lr;
          int kc = kk * 4 + quad;
          bf16x8 kf = *(const bf16x8*)(&Ks[buf][(r * 16 + (kc ^ (r & 15))) * 8]);
          sv[nn] = MFMA16(qf[kk], kf, sv[nn]);
        }
      }

      // p = exp2(s*c), masked to 0 beyond causal; per-lane row sums; P -> LDS (A-layout)
#pragma unroll
      for (int nn = 0; nn < 4; ++nn) {
        int kj = kbase + nn * 16 + lr;
#pragma unroll
        for (int r = 0; r < 4; ++r) {
          int qi = qrow + quad * 4 + r;
          float p = __builtin_amdgcn_exp2f(sv[nn][r] * c_e2); // v_exp_f32
          p = (kj > qi) ? 0.f : p;
          lsum[r] += p;
          Ps[wid][(quad * 4 + r) * LPS + nn * 16 + lr] = (__bf16)p;
        }
      }
      asm volatile("s_waitcnt lgkmcnt(0)" ::: "memory");

      // O += P @ V : A = P[m=qi][k=kj], B = Vs[n=d][k=kj]
#pragma unroll
      for (int kc0 = 0; kc0 < 2; ++kc0) {
        bf16x8 pf = *(const bf16x8*)(&Ps[wid][lr * LPS + kc0 * 32 + quad * 8]);
#pragma unroll
        for (int dd = 0; dd < 8; ++dd) {
          int r = dd * 16 + lr;
          int kc = kc0 * 4 + quad;
          bf16x8 vf = *(const bf16x8*)(&Vs[buf][(r * 8 + (kc ^ (r & 7))) * 8]);
          acc_o[dd] = MFMA16(pf, vf, acc_o[dd]);
        }
      }
    };

    // prologue
    stage(0, 0);
    int cur = 0;
    // steady state: prefetch t+1, counted-wait for t, compute t
    for (int kt = 0; kt < ntiles - 1; ++kt) {
      stage(kt + 1, cur ^ 1);
      asm volatile("s_waitcnt vmcnt(8)" ::: "memory"); // own 8 loads of buf[cur] done
      __builtin_amdgcn_sched_barrier(0);
      __builtin_amdgcn_s_barrier();                    // all waves' parts of buf[cur] visible
      __builtin_amdgcn_sched_barrier(0);
      compute(kt, cur);
      __builtin_amdgcn_sched_barrier(0);
      __builtin_amdgcn_s_barrier();                    // protect buf[cur] before restage next iter
      __builtin_amdgcn_sched_barrier(0);
      cur ^= 1;
    }
    // last tile: full drain
    asm volatile("s_waitcnt vmcnt(0)" ::: "memory");
    __builtin_amdgcn_sched_barrier(0);
    __builtin_amdgcn_s_barrier();
    __builtin_amdgcn_sched_barrier(0);
    compute(ntiles - 1, cur);

    // one reduction of row sums across the quad's 16 lanes
#pragma unroll
    for (int off = 1; off < 16; off <<= 1)
#pragma unroll
      for (int r = 0; r < 4; ++r)
        lsum[r] += __shfl_xor(lsum[r], off, 64);
#pragma unroll
    for (int r = 0; r < 4; ++r) lsum[r] = 1.0f / lsum[r];

#pragma unroll
    for (int dd = 0; dd < 8; ++dd)
#pragma unroll
      for (int r = 0; r < 4; ++r) {
        int row = qrow + quad * 4 + r;
        int col = h * 128 + dd * 16 + lr;
        y[(size_t)row * C + col] = (__bf16)(acc_o[dd][r] * lsum[r]);
      }

    // protect Ks/Vs/Ps before the second triangle reuses them
    __syncthreads();
  }
}

// ---------------------------------------------------------------- launcher
extern "C" void kernel_launch(void* const* d_in, const int* in_sizes, int n_in,
                              void* d_out, int out_size, void* d_ws, size_t ws_size,
                              hipStream_t stream) {
  const float* x      = (const float*)d_in[0];
  const float* cosp   = (const float*)d_in[1];
  const float* sinp   = (const float*)d_in[2];
  const float* W_attn = (const float*)d_in[3];
  const float* b_attn = (const float*)d_in[4];
  const float* W_proj = (const float*)d_in[5];
  const float* b_proj = (const float*)d_in[6];
  float* out = (float*)d_out;

  // workspace layout (bytes), all 16B aligned; total 234,881,024
  char* wsb = (char*)d_ws;
  __bf16* Wab  = (__bf16*)(wsb + 0);          // 12288*4096*2 = 100663296
  __bf16* Wpb  = (__bf16*)(wsb + 100663296);  // 4096*4096*2  =  33554432
  __bf16* xb   = (__bf16*)(wsb + 134217728);  // 2048*4096*2  =  16777216
  __bf16* qkvb = (__bf16*)(wsb + 150994944);  // 2048*12288*2 =  50331648
  __bf16* yb   = (__bf16*)(wsb + 201326592);  // 2048*4096*2  =  16777216
  __bf16* vtb  = (__bf16*)(wsb + 218103808);  // 32*128*2048*2=  16777216

  cvt_f32_to_bf16<<<8192, 256, 0, stream>>>(x, xb, (T * C) / 4);
  cvt_f32_to_bf16<<<49152, 256, 0, stream>>>(W_attn, Wab, (QKV_N * C) / 4);
  cvt_f32_to_bf16<<<16384, 256, 0, stream>>>(W_proj, Wpb, (C * C) / 4);

  // qkv = x @ W_attn^T + b_attn   (M=2048, N=12288, K=4096)
  gemm_bt<1><<<dim3(96, 16), 256, 0, stream>>>(xb, Wab, b_attn, (void*)qkvb, T, QKV_N, C);

  rope_kernel<<<8192, 256, 0, stream>>>(qkvb, cosp, sinp);
  vtrans_kernel<<<dim3(32, 32), 256, 0, stream>>>(qkvb, vtb);

  // 512 blocks = 512 resident slots (2/CU); each block does qb=pair and qb=31-pair
  attn_kernel<<<dim3(32, 16), 256, 0, stream>>>(qkvb, vtb, yb);

  // out = y @ W_proj^T + b_proj   (M=2048, N=4096, K=4096), fp32 out
  gemm_bt<0><<<dim3(32, 16), 256, 0, stream>>>(yb, Wpb, b_proj, (void*)out, T, C, C);
}